// Round 10
// baseline (371.701 us; speedup 1.0000x reference)
//
#include <hip/hip_runtime.h>

#define TT   512
#define CH   128
#define HWP  784        // 28*28
#define NSEG 8
#define NOUT 51380224   // 512*128*784

typedef short bf16x8  __attribute__((ext_vector_type(8)));
typedef float f32x4   __attribute__((ext_vector_type(4)));
typedef float f32x16  __attribute__((ext_vector_type(16)));
typedef int   i32x4   __attribute__((ext_vector_type(4)));
typedef unsigned short u16x4 __attribute__((ext_vector_type(4)));
typedef unsigned short u16x8 __attribute__((ext_vector_type(8)));

__device__ inline unsigned short f2bf(float f) {
    unsigned u = __builtin_bit_cast(unsigned, f);
    u += 0x7fffu + ((u >> 16) & 1u);          // RNE
    return (unsigned short)(u >> 16);
}

__device__ inline void gld_lds16(const void* g, void* l) {
    __builtin_amdgcn_global_load_lds(
        (const __attribute__((address_space(1))) void*)g,
        (__attribute__((address_space(3))) void*)l, 16, 0, 0);
}

#define MFMA32(A, B, C) __builtin_amdgcn_mfma_f32_32x32x16_bf16(A, B, C, 0, 0, 0)

// ---------------------------------------------------------------------------
// Spatial weight repack for 32x32x16 MFMA, frag-major (unchanged):
// frag f = tap*8+ks, block m: lane l = kgrp*32 + (co&31), elem e: ci = ks*16+kgrp*8+e
// ---------------------------------------------------------------------------
__global__ void repack_wsp(const float* __restrict__ w, short* __restrict__ wA) {
    int s = blockIdx.x * 256 + threadIdx.x;
    if (s >= 128 * 128 * 9) return;
    int co = s / 1152, r = s % 1152, ci = r / 9, kh = (r % 9) / 3, kw = r % 3;
    int tap = kh * 3 + kw;
    int m = co >> 5, row = co & 31;
    int ks = ci >> 4, kgrp = (ci >> 3) & 1, e = ci & 7;
    int lane = kgrp * 32 + row;
    int dst = (((tap * 8 + ks) * 4 + m) * 64 + lane) * 8 + e;
    wA[dst] = (short)f2bf(w[s]);
}

// ---------------------------------------------------------------------------
// Temporal weight repack (identity ci order, 16x16x32 frag-major, unchanged)
// ---------------------------------------------------------------------------
__global__ void repack_wt2(const float* __restrict__ w, short* __restrict__ wAt) {
    int s = blockIdx.x * 256 + threadIdx.x;
    if (s >= 128 * 128 * 3) return;
    int o = s / 384, r = s % 384, i = r / 3, tap = r % 3;
    int dst = tap * 16384 + (o >> 4) * 2048 + (i >> 5) * 512 +
              ((i >> 3) & 3) * 128 + (o & 15) * 8 + (i & 7);
    wAt[dst] = (short)f2bf(w[s]);
}

// ---------------------------------------------------------------------------
// Spatial 3x3 conv via mfma_f32_32x32x16_bf16. grid (4, 512), block 512.
// Block: 8 rows x 128 co = 224 px = 7 exact 32-px tiles.
// 10-row LDS window [10][30 st][128 ci] bf16, slot swizzle slot'=slot^(st&15).
// Waves: ch(2 co-halves) x pg(4): wave = 64 co (m=2) x 2 tiles.
// Per tap: ONE load phase (16 A global + 16 B ds_read into regs), one
// sched_barrier-fenced waitcnt drain, then 32 back-to-back MFMAs (1024 cy).
// 2 waves/SIMD (VGPR~212, launch_bounds(512,2)) de-phase: one drains while
// the sibling runs MFMA. Epilogue: acc -> LDS bounce -> contiguous stores.
// ---------------------------------------------------------------------------
__global__ __launch_bounds__(512, 2) void spatial_mfma(
    const float* __restrict__ x, const short* __restrict__ wA,
    const float* __restrict__ b_sp, unsigned short* __restrict__ yT)
{
    __shared__ __align__(16) short xs[300 * 128];   // 76800 B
    char* xsb = (char*)xs;
    const int t = blockIdx.y;
    const int r0 = blockIdx.x * 8;
    const int rows = (28 - r0 < 8) ? (28 - r0) : 8;
    const int pxcnt = rows * 28;
    const int tid = threadIdx.x;

    // ---- stage 10-row window, conflict-free writes (lane = ci-pair) ----
    for (int u = tid; u < 4480; u += 512) {
        int cp = u & 63, q = u >> 6;         // q 0..69
        int rl = q / 7, g = q % 7;
        int rr = r0 - 1 + rl;
        float4 f0 = make_float4(0.f, 0.f, 0.f, 0.f), f1 = f0;
        if (rr >= 0 && rr < 28) {
            const float* px0 = &x[((size_t)(t * CH + 2 * cp)) * HWP + rr * 28 + g * 4];
            f0 = *(const float4*)px0;
            f1 = *(const float4*)(px0 + HWP);
        }
        unsigned u0[4] = {__builtin_bit_cast(unsigned, f0.x), __builtin_bit_cast(unsigned, f0.y),
                          __builtin_bit_cast(unsigned, f0.z), __builtin_bit_cast(unsigned, f0.w)};
        unsigned u1[4] = {__builtin_bit_cast(unsigned, f1.x), __builtin_bit_cast(unsigned, f1.y),
                          __builtin_bit_cast(unsigned, f1.z), __builtin_bit_cast(unsigned, f1.w)};
        int stb = rl * 30 + g * 4 + 1;
#pragma unroll
        for (int j = 0; j < 4; ++j) {
            int st = stb + j;
            unsigned val = __builtin_amdgcn_perm(u1[j], u0[j], 0x07060302u);
            int addr = (st << 8) | (((cp >> 2) ^ (st & 15)) << 4) | ((cp & 3) << 2);
            *(unsigned*)(xsb + addr) = val;
        }
    }
    // ---- zero pad columns: st = r*30 + {0,29}, r = 0..9 ----
    for (int v = tid; v < 1280; v += 512) {
        int cp = v & 63, k = v >> 6;         // k 0..19
        int st = (k >> 1) * 30 + (k & 1) * 29;
        int addr = (st << 8) | (((cp >> 2) ^ (st & 15)) << 4) | ((cp & 3) << 2);
        *(unsigned*)(xsb + addr) = 0u;
    }
    __syncthreads();

    const int wid = tid >> 6, l = tid & 63;
    const int l31 = l & 31, bb5 = l >> 5;
    const int ch = wid & 1, pg = wid >> 1;
    const int ch2 = ch * 2;
    const int tI0 = pg * 2, tI1 = pg * 2 + 1;

    const int p0 = tI0 * 32 + l31;
    const int p1 = tI1 * 32 + l31;
    const bool ok1t = (tI1 < 7);
    const int pc0 = (p0 < pxcnt) ? p0 : 0;
    const int pc1 = (ok1t && p1 < pxcnt) ? p1 : 0;
    const int st0_0 = (pc0 / 28 + 1) * 30 + pc0 % 28 + 1;
    const int st0_1 = (pc1 / 28 + 1) * 30 + pc1 % 28 + 1;

    f32x16 zz = {};
    f32x16 acc00 = zz, acc10 = zz;           // [m][tile0]
    f32x16 acc01 = zz, acc11 = zz;           // [m][tile1]

    const bf16x8* wv = (const bf16x8*)wA;

    for (int tap = 0; tap < 9; ++tap) {
        const int off = (tap / 3 - 1) * 30 + (tap % 3) - 1;
        const int stv0 = st0_0 + off, stv1 = st0_1 + off;
        const int rb0 = stv0 << 8, sw0 = stv0 & 15;
        const int rb1 = stv1 << 8, sw1 = stv1 & 15;

        // ---- load phase: 16 A (global) + 16 B (LDS) into registers ----
        bf16x8 A[16];
#pragma unroll
        for (int k2 = 0; k2 < 16; ++k2)
            A[k2] = wv[((tap * 8 + (k2 >> 1)) * 4 + ch2 + (k2 & 1)) * 64 + l];
        i32x4 B0[8], B1[8];
#pragma unroll
        for (int ks = 0; ks < 8; ++ks) {
            B0[ks] = *(const i32x4*)(xsb + (rb0 | (((ks * 2 + bb5) ^ sw0) << 4)));
            B1[ks] = *(const i32x4*)(xsb + (rb1 | (((ks * 2 + bb5) ^ sw1) << 4)));
        }
        // ---- fence: nothing moves across; one drain per tap ----
        __builtin_amdgcn_sched_barrier(0);
        asm volatile("s_waitcnt vmcnt(0) lgkmcnt(0)" ::: "memory");
        __builtin_amdgcn_sched_barrier(0);
        // ---- 32 back-to-back MFMAs ----
        __builtin_amdgcn_s_setprio(1);
#pragma unroll
        for (int ks = 0; ks < 8; ++ks) {
            bf16x8 f0 = __builtin_bit_cast(bf16x8, B0[ks]);
            bf16x8 f1 = __builtin_bit_cast(bf16x8, B1[ks]);
            acc00 = MFMA32(A[ks * 2],     f0, acc00);
            acc10 = MFMA32(A[ks * 2 + 1], f0, acc10);
            acc01 = MFMA32(A[ks * 2],     f1, acc01);
            acc11 = MFMA32(A[ks * 2 + 1], f1, acc11);
        }
        __builtin_amdgcn_s_setprio(0);
        __builtin_amdgcn_sched_barrier(0);
    }

    // ---- epilogue: window dead; bounce acc through LDS for contiguity ----
    __syncthreads();
    const int wbase = wid * 8704;             // 2 tiles x 32 px x 136 B
#pragma unroll
    for (int mi = 0; mi < 2; ++mi) {
#pragma unroll
        for (int r2 = 0; r2 < 4; ++r2) {
            int cb = (ch2 + mi) * 32 + 8 * r2 + 4 * bb5;
            float4 bs = *(const float4*)&b_sp[cb];
            float bsa[4] = {bs.x, bs.y, bs.z, bs.w};
            u16x4 k0, k1;
#pragma unroll
            for (int q = 0; q < 4; ++q) {
                k0[q] = f2bf((mi ? acc10[r2 * 4 + q] : acc00[r2 * 4 + q]) + bsa[q]);
                k1[q] = f2bf((mi ? acc11[r2 * 4 + q] : acc01[r2 * 4 + q]) + bsa[q]);
            }
            int co_off = (mi * 32 + 8 * r2 + 4 * bb5) * 2;   // within 64-ch half
            *(u16x4*)(xsb + wbase + l31 * 136 + co_off) = k0;
            *(u16x4*)(xsb + wbase + 4352 + l31 * 136 + co_off) = k1;
        }
    }
    // wave-private region: compiler inserts lgkmcnt before dependent reads
#pragma unroll
    for (int tt2 = 0; tt2 < 2; ++tt2) {
        int tI = tt2 ? tI1 : tI0;
#pragma unroll
        for (int j = 0; j < 4; ++j) {
            int idx = j * 64 + l;
            int pxl = idx >> 3, sub = idx & 7;
            u16x8 v = *(const u16x8*)(xsb + wbase + tt2 * 4352 + pxl * 136 + sub * 16);
            int p = tI * 32 + pxl;
            if (tI < 7 && p < pxcnt) {
                char* dst = (char*)yT + ((size_t)t * HWP + r0 * 28 + p) * 256 +
                            ch * 128 + sub * 16;
                *(u16x8*)dst = v;
            }
        }
    }
}

// ---------------------------------------------------------------------------
// Ragged temporal conv: 4-wave blocks, async LDS-staged B, double-buffered.
// grid (7, 512), block 256. (unchanged — near HBM roofline)
// ---------------------------------------------------------------------------
__global__ __launch_bounds__(256, 4) void temporal_mfma(
    const unsigned short* __restrict__ yT, const short* __restrict__ wAt,
    const float* __restrict__ b_t, const float* __restrict__ alpha,
    const float* __restrict__ x, const int* __restrict__ vid_lens,
    float* __restrict__ out)
{
    __shared__ __align__(16) char ldsT[29696];   // 2x14336 stage | 4x7424 epi

    const int chunk = blockIdx.x, t = blockIdx.y;
    const int tid = threadIdx.x, wid = tid >> 6, l = tid & 63;
    const int l15 = l & 15, kgrp = l >> 4;
    const int sx = l15 & 7;

    bool isS = false, isE = false;
    {
        int cum = 0;
        for (int s = 0; s < NSEG; ++s) {
            if (t == cum) isS = true;
            cum += vid_lens[s];
            if (t == cum - 1) isE = true;
        }
    }
    const bool tapAct[3] = {!isS, true, !isE};

    auto stage = [&](int s) {
        int tap = s >> 1, kp = s & 1;
        if (!tapAct[tap]) return;
        int tp = t + tap - 1;
        const char* yb = (const char*)yT + (size_t)tp * HWP * 256;
        char* buf = ldsT + (s & 1) * 14336;
#pragma unroll
        for (int r = 0; r < 4; ++r) {
            int c = r * 256 + wid * 64 + l;
            if (r < 3 || wid < 2) {                    // c < 896, wave-uniform
                int px = c >> 3, sp = c & 7;
                int ssrc = sp ^ (px & 7);
                const char* g = yb + ((size_t)(chunk * 112 + px)) * 256 + kp * 128 + ssrc * 16;
                char* ldst = buf + (r * 256 + wid * 64) * 16;
                gld_lds16(g, ldst);
            }
        }
    };

    f32x4 acc[2][7];
#pragma unroll
    for (int m = 0; m < 2; ++m)
#pragma unroll
        for (int n = 0; n < 7; ++n) acc[m][n] = (f32x4){0.f, 0.f, 0.f, 0.f};

    const bf16x8* wAv = (const bf16x8*)wAt;

    stage(0);
    __syncthreads();

    for (int s = 0; s < 6; ++s) {
        if (s < 5) stage(s + 1);
        int tap = s >> 1, kp = s & 1;
        if (tapAct[tap]) {
            const char* buf = ldsT + (s & 1) * 14336;
            bf16x8 a[2][2];
#pragma unroll
            for (int m = 0; m < 2; ++m)
#pragma unroll
                for (int k1 = 0; k1 < 2; ++k1)
                    a[m][k1] = wAv[((tap * 8 + wid * 2 + m) * 4 + kp * 2 + k1) * 64 + l];
            __builtin_amdgcn_s_setprio(1);
#pragma unroll
            for (int k1 = 0; k1 < 2; ++k1) {
#pragma unroll
                for (int nf = 0; nf < 7; ++nf) {
                    int addr = (nf * 16 + l15) * 128 + ((k1 * 4 + kgrp) ^ sx) * 16;
                    i32x4 bi = *(const i32x4*)(buf + addr);
                    bf16x8 b = __builtin_bit_cast(bf16x8, bi);
                    acc[0][nf] = __builtin_amdgcn_mfma_f32_16x16x32_bf16(a[0][k1], b, acc[0][nf], 0, 0, 0);
                    acc[1][nf] = __builtin_amdgcn_mfma_f32_16x16x32_bf16(a[1][k1], b, acc[1][nf], 0, 0, 0);
                }
            }
            __builtin_amdgcn_s_setprio(0);
        }
        __syncthreads();
    }

    // ---- epilogue: LDS transpose -> coalesced bias/PReLU/residual/store ----
    float* fl = (float*)ldsT;
    const int wbase = wid * 1856;            // 16 co x 116 px-stride floats
#pragma unroll
    for (int m = 0; m < 2; ++m) {
#pragma unroll
        for (int nf = 0; nf < 7; ++nf)
#pragma unroll
            for (int rr = 0; rr < 4; ++rr)
                fl[wbase + (kgrp * 4 + rr) * 116 + nf * 16 + l15] = acc[m][nf][rr];
#pragma unroll
        for (int j = 0; j < 7; ++j) {
            int idx = j * 64 + l;
            int co_r = idx / 28, q = idx % 28;
            f32x4 v4 = *(const f32x4*)&fl[wbase + co_r * 116 + q * 4];
            int co_g = wid * 32 + m * 16 + co_r;
            float bt = b_t[co_g], al = alpha[co_g];
            size_t gi = ((size_t)(t * CH + co_g)) * HWP + chunk * 112 + q * 4;
            float4 xv = *(const float4*)&x[gi];
            float xr[4] = {xv.x, xv.y, xv.z, xv.w};
            float rrv[4];
#pragma unroll
            for (int e = 0; e < 4; ++e) {
                float v = v4[e] + bt;
                v = (v >= 0.f) ? v : al * v;
                rrv[e] = v + xr[e];
            }
            *(float4*)&out[gi] = make_float4(rrv[0], rrv[1], rrv[2], rrv[3]);
        }
        __syncthreads();   // all waves done with region before m=1 reuse
    }
}

// ---------------------------------------------------------------------------
__global__ void write_lens(const int* __restrict__ vid_lens, float* __restrict__ out) {
    int i = threadIdx.x;
    if (i < NSEG) out[NOUT + i] = (float)vid_lens[i];
}

// ---------------------------------------------------------------------------
extern "C" void kernel_launch(void* const* d_in, const int* in_sizes, int n_in,
                              void* d_out, int out_size, void* d_ws, size_t ws_size,
                              hipStream_t stream) {
    const float* x        = (const float*)d_in[0];
    const int*   vid_lens = (const int*)d_in[1];
    const float* w_sp     = (const float*)d_in[2];
    const float* b_sp     = (const float*)d_in[3];
    const float* w_t      = (const float*)d_in[4];
    const float* b_t      = (const float*)d_in[5];
    const float* alpha    = (const float*)d_in[6];
    float* out = (float*)d_out;

    unsigned short* yT = (unsigned short*)d_ws;                       // 102,760,448 B
    short* wA  = (short*)((char*)d_ws + 102760448);                   //    294,912 B
    short* wAt = (short*)((char*)d_ws + 102760448 + 294912);          //     98,304 B

    repack_wsp<<<576, 256, 0, stream>>>(w_sp, wA);
    repack_wt2<<<192, 256, 0, stream>>>(w_t, wAt);
    spatial_mfma<<<dim3(4, 512), 512, 0, stream>>>(x, wA, b_sp, yT);
    temporal_mfma<<<dim3(7, 512), 256, 0, stream>>>(yT, wAt, b_t, alpha, x, vid_lens, out);
    write_lens<<<1, 64, 0, stream>>>(vid_lens, out);
}

// Round 11
// 360.957 us; speedup vs baseline: 1.0298x; 1.0298x over previous
//
#include <hip/hip_runtime.h>

#define TT   512
#define CH   128
#define HWP  784        // 28*28
#define NSEG 8
#define NOUT 51380224   // 512*128*784

typedef short bf16x8  __attribute__((ext_vector_type(8)));
typedef float f32x4   __attribute__((ext_vector_type(4)));
typedef float f32x16  __attribute__((ext_vector_type(16)));
typedef int   i32x4   __attribute__((ext_vector_type(4)));
typedef unsigned short u16x4 __attribute__((ext_vector_type(4)));
typedef unsigned short u16x8 __attribute__((ext_vector_type(8)));

__device__ inline unsigned short f2bf(float f) {
    unsigned u = __builtin_bit_cast(unsigned, f);
    u += 0x7fffu + ((u >> 16) & 1u);          // RNE
    return (unsigned short)(u >> 16);
}

__device__ inline void gld_lds16(const void* g, void* l) {
    __builtin_amdgcn_global_load_lds(
        (const __attribute__((address_space(1))) void*)g,
        (__attribute__((address_space(3))) void*)l, 16, 0, 0);
}

#define MFMA32(A, B, C) __builtin_amdgcn_mfma_f32_32x32x16_bf16(A, B, C, 0, 0, 0)
#define BC8(x) __builtin_bit_cast(bf16x8, x)

__device__ __forceinline__ i32x4 ldB(const char* xsb, int rb, int sw, int slot) {
    return *(const i32x4*)(xsb + (rb | ((slot ^ sw) << 4)));
}

// ---------------------------------------------------------------------------
// Spatial weight repack for 32x32x16 MFMA, frag-major (unchanged):
// frag f = tap*8+ks, block m: lane l = kgrp*32 + (co&31), elem e: ci = ks*16+kgrp*8+e
// ---------------------------------------------------------------------------
__global__ void repack_wsp(const float* __restrict__ w, short* __restrict__ wA) {
    int s = blockIdx.x * 256 + threadIdx.x;
    if (s >= 128 * 128 * 9) return;
    int co = s / 1152, r = s % 1152, ci = r / 9, kh = (r % 9) / 3, kw = r % 3;
    int tap = kh * 3 + kw;
    int m = co >> 5, row = co & 31;
    int ks = ci >> 4, kgrp = (ci >> 3) & 1, e = ci & 7;
    int lane = kgrp * 32 + row;
    int dst = (((tap * 8 + ks) * 4 + m) * 64 + lane) * 8 + e;
    wA[dst] = (short)f2bf(w[s]);
}

// ---------------------------------------------------------------------------
// Temporal weight repack (identity ci order, 16x16x32 frag-major, unchanged)
// ---------------------------------------------------------------------------
__global__ void repack_wt2(const float* __restrict__ w, short* __restrict__ wAt) {
    int s = blockIdx.x * 256 + threadIdx.x;
    if (s >= 128 * 128 * 3) return;
    int o = s / 384, r = s % 384, i = r / 3, tap = r % 3;
    int dst = tap * 16384 + (o >> 4) * 2048 + (i >> 5) * 512 +
              ((i >> 3) & 3) * 128 + (o & 15) * 8 + (i & 7);
    wAt[dst] = (short)f2bf(w[s]);
}

// ---- issue 8 A-frag loads for half HH into named regs (opaque to sched) ----
#define ISSUE_A(HH, R0, R1, R2, R3, R4, R5, R6, R7) do {                         \
    const char* pA_ = wAl + ((HH) >> 1) * 32768 + ((HH) & 1) * 16384;            \
    const char* pB_ = pA_ + 4096;                                                \
    const char* pC_ = pA_ + 8192;                                                \
    const char* pD_ = pA_ + 12288;                                               \
    asm volatile("global_load_dwordx4 %0, %1, off"             : "=v"(R0) : "v"(pA_)); \
    asm volatile("global_load_dwordx4 %0, %1, off offset:1024" : "=v"(R1) : "v"(pA_)); \
    asm volatile("global_load_dwordx4 %0, %1, off"             : "=v"(R2) : "v"(pB_)); \
    asm volatile("global_load_dwordx4 %0, %1, off offset:1024" : "=v"(R3) : "v"(pB_)); \
    asm volatile("global_load_dwordx4 %0, %1, off"             : "=v"(R4) : "v"(pC_)); \
    asm volatile("global_load_dwordx4 %0, %1, off offset:1024" : "=v"(R5) : "v"(pC_)); \
    asm volatile("global_load_dwordx4 %0, %1, off"             : "=v"(R6) : "v"(pD_)); \
    asm volatile("global_load_dwordx4 %0, %1, off offset:1024" : "=v"(R7) : "v"(pD_)); \
} while (0)

// ---- one half-tap: 8 B ds_reads, counted wait, 16 MFMAs ----
#define HALF_BODY(LASTWAIT, HODD, R0, R1, R2, R3, R4, R5, R6, R7) do {           \
    i32x4 b00 = ldB(xsb, rb0, sw0, (HODD) * 8 + 0 + bb5);                        \
    i32x4 b01 = ldB(xsb, rb0, sw0, (HODD) * 8 + 2 + bb5);                        \
    i32x4 b02 = ldB(xsb, rb0, sw0, (HODD) * 8 + 4 + bb5);                        \
    i32x4 b03 = ldB(xsb, rb0, sw0, (HODD) * 8 + 6 + bb5);                        \
    i32x4 b10 = ldB(xsb, rb1, sw1, (HODD) * 8 + 0 + bb5);                        \
    i32x4 b11 = ldB(xsb, rb1, sw1, (HODD) * 8 + 2 + bb5);                        \
    i32x4 b12 = ldB(xsb, rb1, sw1, (HODD) * 8 + 4 + bb5);                        \
    i32x4 b13 = ldB(xsb, rb1, sw1, (HODD) * 8 + 6 + bb5);                        \
    if (LASTWAIT) { asm volatile("s_waitcnt vmcnt(0) lgkmcnt(0)" ::: "memory"); }\
    else          { asm volatile("s_waitcnt vmcnt(8) lgkmcnt(0)" ::: "memory"); }\
    __builtin_amdgcn_sched_barrier(0);                                           \
    __builtin_amdgcn_s_setprio(1);                                               \
    acc00 = MFMA32(BC8(R0), BC8(b00), acc00);                                    \
    acc10 = MFMA32(BC8(R1), BC8(b00), acc10);                                    \
    acc01 = MFMA32(BC8(R0), BC8(b10), acc01);                                    \
    acc11 = MFMA32(BC8(R1), BC8(b10), acc11);                                    \
    acc00 = MFMA32(BC8(R2), BC8(b01), acc00);                                    \
    acc10 = MFMA32(BC8(R3), BC8(b01), acc10);                                    \
    acc01 = MFMA32(BC8(R2), BC8(b11), acc01);                                    \
    acc11 = MFMA32(BC8(R3), BC8(b11), acc11);                                    \
    acc00 = MFMA32(BC8(R4), BC8(b02), acc00);                                    \
    acc10 = MFMA32(BC8(R5), BC8(b02), acc10);                                    \
    acc01 = MFMA32(BC8(R4), BC8(b12), acc01);                                    \
    acc11 = MFMA32(BC8(R5), BC8(b12), acc11);                                    \
    acc00 = MFMA32(BC8(R6), BC8(b03), acc00);                                    \
    acc10 = MFMA32(BC8(R7), BC8(b03), acc10);                                    \
    acc01 = MFMA32(BC8(R6), BC8(b13), acc01);                                    \
    acc11 = MFMA32(BC8(R7), BC8(b13), acc11);                                    \
    __builtin_amdgcn_s_setprio(0);                                               \
    __builtin_amdgcn_sched_barrier(0);                                           \
} while (0)

// ---------------------------------------------------------------------------
// Spatial 3x3 conv via mfma_f32_32x32x16_bf16. grid (4, 512), block 512.
// Block: 8 rows x 128 co = 224 px = 7 exact 32-px tiles.
// 10-row LDS window [10][30 st][128 ci] bf16, slot swizzle slot'=slot^(st&15).
// Waves: ch(2 co-halves) x pg(4): wave = 64 co (m=2) x 2 tiles.
// K-loop: asm global_load A double-buffer (half-tap granularity), counted
// s_waitcnt vmcnt(8) (T4: never drain to 0), sched_barrier-fenced MFMA
// clusters. A-loads are volatile asm -> cannot be sunk/rematerialized.
// Epilogue: acc -> LDS bounce -> 128B-contiguous u16x8 stores.
// ---------------------------------------------------------------------------
__global__ __launch_bounds__(512, 2) void spatial_mfma(
    const float* __restrict__ x, const short* __restrict__ wA,
    const float* __restrict__ b_sp, unsigned short* __restrict__ yT)
{
    __shared__ __align__(16) short xs[300 * 128];   // 76800 B
    char* xsb = (char*)xs;
    const int t = blockIdx.y;
    const int r0 = blockIdx.x * 8;
    const int rows = (28 - r0 < 8) ? (28 - r0) : 8;
    const int pxcnt = rows * 28;
    const int tid = threadIdx.x;

    // ---- stage 10-row window, conflict-free writes (lane = ci-pair) ----
    for (int u = tid; u < 4480; u += 512) {
        int cp = u & 63, q = u >> 6;         // q 0..69
        int rl = q / 7, g = q % 7;
        int rr = r0 - 1 + rl;
        float4 f0 = make_float4(0.f, 0.f, 0.f, 0.f), f1 = f0;
        if (rr >= 0 && rr < 28) {
            const float* px0 = &x[((size_t)(t * CH + 2 * cp)) * HWP + rr * 28 + g * 4];
            f0 = *(const float4*)px0;
            f1 = *(const float4*)(px0 + HWP);
        }
        unsigned u0[4] = {__builtin_bit_cast(unsigned, f0.x), __builtin_bit_cast(unsigned, f0.y),
                          __builtin_bit_cast(unsigned, f0.z), __builtin_bit_cast(unsigned, f0.w)};
        unsigned u1[4] = {__builtin_bit_cast(unsigned, f1.x), __builtin_bit_cast(unsigned, f1.y),
                          __builtin_bit_cast(unsigned, f1.z), __builtin_bit_cast(unsigned, f1.w)};
        int stb = rl * 30 + g * 4 + 1;
#pragma unroll
        for (int j = 0; j < 4; ++j) {
            int st = stb + j;
            unsigned val = __builtin_amdgcn_perm(u1[j], u0[j], 0x07060302u);
            int addr = (st << 8) | (((cp >> 2) ^ (st & 15)) << 4) | ((cp & 3) << 2);
            *(unsigned*)(xsb + addr) = val;
        }
    }
    // ---- zero pad columns: st = r*30 + {0,29}, r = 0..9 ----
    for (int v = tid; v < 1280; v += 512) {
        int cp = v & 63, k = v >> 6;         // k 0..19
        int st = (k >> 1) * 30 + (k & 1) * 29;
        int addr = (st << 8) | (((cp >> 2) ^ (st & 15)) << 4) | ((cp & 3) << 2);
        *(unsigned*)(xsb + addr) = 0u;
    }
    __syncthreads();

    const int wid = tid >> 6, l = tid & 63;
    const int l31 = l & 31, bb5 = l >> 5;
    const int ch = wid & 1, pg = wid >> 1;
    const int ch2 = ch * 2;
    const int tI0 = pg * 2, tI1 = pg * 2 + 1;

    const int p0 = tI0 * 32 + l31;
    const int p1 = tI1 * 32 + l31;
    const bool ok1t = (tI1 < 7);
    const int pc0 = (p0 < pxcnt) ? p0 : 0;
    const int pc1 = (ok1t && p1 < pxcnt) ? p1 : 0;
    const int st0_0 = (pc0 / 28 + 1) * 30 + pc0 % 28 + 1;
    const int st0_1 = (pc1 / 28 + 1) * 30 + pc1 % 28 + 1;

    f32x16 zz = {};
    f32x16 acc00 = zz, acc10 = zz;           // [m][tile0]
    f32x16 acc01 = zz, acc11 = zz;           // [m][tile1]

    const char* wAl = (const char*)wA + ch2 * 1024 + l * 16;

    // ---- A double buffer: halves 2T (even) -> A0x, 2T+1 (odd) -> A1x ----
    i32x4 A00, A01, A02, A03, A04, A05, A06, A07;
    i32x4 A10, A11, A12, A13, A14, A15, A16, A17;
    ISSUE_A(0, A00, A01, A02, A03, A04, A05, A06, A07);
    ISSUE_A(1, A10, A11, A12, A13, A14, A15, A16, A17);

#pragma unroll
    for (int tap = 0; tap < 9; ++tap) {
        const int off = (tap / 3 - 1) * 30 + (tap % 3) - 1;
        const int stv0 = st0_0 + off, stv1 = st0_1 + off;
        const int rb0 = stv0 << 8, sw0 = stv0 & 15;
        const int rb1 = stv1 << 8, sw1 = stv1 & 15;

        // even half: uses A0x (arrived; A-odd + possibly next-even in flight)
        HALF_BODY(false, 0, A00, A01, A02, A03, A04, A05, A06, A07);
        if (tap < 8) ISSUE_A(2 * tap + 2, A00, A01, A02, A03, A04, A05, A06, A07);

        // odd half: uses A1x
        HALF_BODY(tap == 8, 1, A10, A11, A12, A13, A14, A15, A16, A17);
        if (tap < 8) ISSUE_A(2 * tap + 3, A10, A11, A12, A13, A14, A15, A16, A17);
    }

    // ---- epilogue: window dead; bounce acc through LDS for contiguity ----
    __syncthreads();
    const int wbase = wid * 8704;             // 2 tiles x 32 px x 136 B
#pragma unroll
    for (int mi = 0; mi < 2; ++mi) {
#pragma unroll
        for (int r2 = 0; r2 < 4; ++r2) {
            int cb = (ch2 + mi) * 32 + 8 * r2 + 4 * bb5;
            float4 bs = *(const float4*)&b_sp[cb];
            float bsa[4] = {bs.x, bs.y, bs.z, bs.w};
            u16x4 k0, k1;
#pragma unroll
            for (int q = 0; q < 4; ++q) {
                k0[q] = f2bf((mi ? acc10[r2 * 4 + q] : acc00[r2 * 4 + q]) + bsa[q]);
                k1[q] = f2bf((mi ? acc11[r2 * 4 + q] : acc01[r2 * 4 + q]) + bsa[q]);
            }
            int co_off = (mi * 32 + 8 * r2 + 4 * bb5) * 2;   // within 64-ch half
            *(u16x4*)(xsb + wbase + l31 * 136 + co_off) = k0;
            *(u16x4*)(xsb + wbase + 4352 + l31 * 136 + co_off) = k1;
        }
    }
    // wave-private region: compiler inserts lgkmcnt before dependent reads
#pragma unroll
    for (int tt2 = 0; tt2 < 2; ++tt2) {
        int tI = tt2 ? tI1 : tI0;
#pragma unroll
        for (int j = 0; j < 4; ++j) {
            int idx = j * 64 + l;
            int pxl = idx >> 3, sub = idx & 7;
            u16x8 v = *(const u16x8*)(xsb + wbase + tt2 * 4352 + pxl * 136 + sub * 16);
            int p = tI * 32 + pxl;
            if (tI < 7 && p < pxcnt) {
                char* dst = (char*)yT + ((size_t)t * HWP + r0 * 28 + p) * 256 +
                            ch * 128 + sub * 16;
                *(u16x8*)dst = v;
            }
        }
    }
}

// ---------------------------------------------------------------------------
// Ragged temporal conv: 4-wave blocks, async LDS-staged B, double-buffered.
// grid (7, 512), block 256. (unchanged — near HBM roofline)
// ---------------------------------------------------------------------------
__global__ __launch_bounds__(256, 4) void temporal_mfma(
    const unsigned short* __restrict__ yT, const short* __restrict__ wAt,
    const float* __restrict__ b_t, const float* __restrict__ alpha,
    const float* __restrict__ x, const int* __restrict__ vid_lens,
    float* __restrict__ out)
{
    __shared__ __align__(16) char ldsT[29696];   // 2x14336 stage | 4x7424 epi

    const int chunk = blockIdx.x, t = blockIdx.y;
    const int tid = threadIdx.x, wid = tid >> 6, l = tid & 63;
    const int l15 = l & 15, kgrp = l >> 4;
    const int sx = l15 & 7;

    bool isS = false, isE = false;
    {
        int cum = 0;
        for (int s = 0; s < NSEG; ++s) {
            if (t == cum) isS = true;
            cum += vid_lens[s];
            if (t == cum - 1) isE = true;
        }
    }
    const bool tapAct[3] = {!isS, true, !isE};

    auto stage = [&](int s) {
        int tap = s >> 1, kp = s & 1;
        if (!tapAct[tap]) return;
        int tp = t + tap - 1;
        const char* yb = (const char*)yT + (size_t)tp * HWP * 256;
        char* buf = ldsT + (s & 1) * 14336;
#pragma unroll
        for (int r = 0; r < 4; ++r) {
            int c = r * 256 + wid * 64 + l;
            if (r < 3 || wid < 2) {                    // c < 896, wave-uniform
                int px = c >> 3, sp = c & 7;
                int ssrc = sp ^ (px & 7);
                const char* g = yb + ((size_t)(chunk * 112 + px)) * 256 + kp * 128 + ssrc * 16;
                char* ldst = buf + (r * 256 + wid * 64) * 16;
                gld_lds16(g, ldst);
            }
        }
    };

    f32x4 acc[2][7];
#pragma unroll
    for (int m = 0; m < 2; ++m)
#pragma unroll
        for (int n = 0; n < 7; ++n) acc[m][n] = (f32x4){0.f, 0.f, 0.f, 0.f};

    const bf16x8* wAv = (const bf16x8*)wAt;

    stage(0);
    __syncthreads();

    for (int s = 0; s < 6; ++s) {
        if (s < 5) stage(s + 1);
        int tap = s >> 1, kp = s & 1;
        if (tapAct[tap]) {
            const char* buf = ldsT + (s & 1) * 14336;
            bf16x8 a[2][2];
#pragma unroll
            for (int m = 0; m < 2; ++m)
#pragma unroll
                for (int k1 = 0; k1 < 2; ++k1)
                    a[m][k1] = wAv[((tap * 8 + wid * 2 + m) * 4 + kp * 2 + k1) * 64 + l];
            __builtin_amdgcn_s_setprio(1);
#pragma unroll
            for (int k1 = 0; k1 < 2; ++k1) {
#pragma unroll
                for (int nf = 0; nf < 7; ++nf) {
                    int addr = (nf * 16 + l15) * 128 + ((k1 * 4 + kgrp) ^ sx) * 16;
                    i32x4 bi = *(const i32x4*)(buf + addr);
                    bf16x8 b = __builtin_bit_cast(bf16x8, bi);
                    acc[0][nf] = __builtin_amdgcn_mfma_f32_16x16x32_bf16(a[0][k1], b, acc[0][nf], 0, 0, 0);
                    acc[1][nf] = __builtin_amdgcn_mfma_f32_16x16x32_bf16(a[1][k1], b, acc[1][nf], 0, 0, 0);
                }
            }
            __builtin_amdgcn_s_setprio(0);
        }
        __syncthreads();
    }

    // ---- epilogue: LDS transpose -> coalesced bias/PReLU/residual/store ----
    float* fl = (float*)ldsT;
    const int wbase = wid * 1856;            // 16 co x 116 px-stride floats
#pragma unroll
    for (int m = 0; m < 2; ++m) {
#pragma unroll
        for (int nf = 0; nf < 7; ++nf)
#pragma unroll
            for (int rr = 0; rr < 4; ++rr)
                fl[wbase + (kgrp * 4 + rr) * 116 + nf * 16 + l15] = acc[m][nf][rr];
#pragma unroll
        for (int j = 0; j < 7; ++j) {
            int idx = j * 64 + l;
            int co_r = idx / 28, q = idx % 28;
            f32x4 v4 = *(const f32x4*)&fl[wbase + co_r * 116 + q * 4];
            int co_g = wid * 32 + m * 16 + co_r;
            float bt = b_t[co_g], al = alpha[co_g];
            size_t gi = ((size_t)(t * CH + co_g)) * HWP + chunk * 112 + q * 4;
            float4 xv = *(const float4*)&x[gi];
            float xr[4] = {xv.x, xv.y, xv.z, xv.w};
            float rrv[4];
#pragma unroll
            for (int e = 0; e < 4; ++e) {
                float v = v4[e] + bt;
                v = (v >= 0.f) ? v : al * v;
                rrv[e] = v + xr[e];
            }
            *(float4*)&out[gi] = make_float4(rrv[0], rrv[1], rrv[2], rrv[3]);
        }
        __syncthreads();   // all waves done with region before m=1 reuse
    }
}

// ---------------------------------------------------------------------------
__global__ void write_lens(const int* __restrict__ vid_lens, float* __restrict__ out) {
    int i = threadIdx.x;
    if (i < NSEG) out[NOUT + i] = (float)vid_lens[i];
}

// ---------------------------------------------------------------------------
extern "C" void kernel_launch(void* const* d_in, const int* in_sizes, int n_in,
                              void* d_out, int out_size, void* d_ws, size_t ws_size,
                              hipStream_t stream) {
    const float* x        = (const float*)d_in[0];
    const int*   vid_lens = (const int*)d_in[1];
    const float* w_sp     = (const float*)d_in[2];
    const float* b_sp     = (const float*)d_in[3];
    const float* w_t      = (const float*)d_in[4];
    const float* b_t      = (const float*)d_in[5];
    const float* alpha    = (const float*)d_in[6];
    float* out = (float*)d_out;

    unsigned short* yT = (unsigned short*)d_ws;                       // 102,760,448 B
    short* wA  = (short*)((char*)d_ws + 102760448);                   //    294,912 B
    short* wAt = (short*)((char*)d_ws + 102760448 + 294912);          //     98,304 B

    repack_wsp<<<576, 256, 0, stream>>>(w_sp, wA);
    repack_wt2<<<192, 256, 0, stream>>>(w_t, wAt);
    spatial_mfma<<<dim3(4, 512), 512, 0, stream>>>(x, wA, b_sp, yT);
    temporal_mfma<<<dim3(7, 512), 256, 0, stream>>>(yT, wAt, b_t, alpha, x, vid_lens, out);
    write_lens<<<1, 64, 0, stream>>>(vid_lens, out);
}

// Round 12
// 333.599 us; speedup vs baseline: 1.1142x; 1.0820x over previous
//
#include <hip/hip_runtime.h>

#define TT   512
#define CH   128
#define HWP  784        // 28*28
#define NSEG 8
#define NOUT 51380224   // 512*128*784

typedef short bf16x8  __attribute__((ext_vector_type(8)));
typedef float f32x4   __attribute__((ext_vector_type(4)));
typedef float f32x16  __attribute__((ext_vector_type(16)));
typedef int   i32x4   __attribute__((ext_vector_type(4)));
typedef unsigned short u16x4 __attribute__((ext_vector_type(4)));
typedef unsigned short u16x8 __attribute__((ext_vector_type(8)));

__device__ inline unsigned short f2bf(float f) {
    unsigned u = __builtin_bit_cast(unsigned, f);
    u += 0x7fffu + ((u >> 16) & 1u);          // RNE
    return (unsigned short)(u >> 16);
}

__device__ inline void gld_lds16(const void* g, void* l) {
    __builtin_amdgcn_global_load_lds(
        (const __attribute__((address_space(1))) void*)g,
        (__attribute__((address_space(3))) void*)l, 16, 0, 0);
}

#define MFMA32(A, B, C) __builtin_amdgcn_mfma_f32_32x32x16_bf16(A, B, C, 0, 0, 0)
#define BC8(x) __builtin_bit_cast(bf16x8, x)

__device__ __forceinline__ i32x4 ldB(const char* xsb, int rb, int sw, int slot) {
    return *(const i32x4*)(xsb + (rb | ((slot ^ sw) << 4)));
}

// ---------------------------------------------------------------------------
// Spatial weight repack for 32x32x16 MFMA, frag-major (unchanged):
// frag f = tap*8+ks, block m: lane l = kgrp*32 + (co&31), elem e: ci = ks*16+kgrp*8+e
// dst = ((f*4 + m)*64 + l)*8 + e   (per tap: 32 KB, linear in (ks,m,l))
// ---------------------------------------------------------------------------
__global__ void repack_wsp(const float* __restrict__ w, short* __restrict__ wA) {
    int s = blockIdx.x * 256 + threadIdx.x;
    if (s >= 128 * 128 * 9) return;
    int co = s / 1152, r = s % 1152, ci = r / 9, kh = (r % 9) / 3, kw = r % 3;
    int tap = kh * 3 + kw;
    int m = co >> 5, row = co & 31;
    int ks = ci >> 4, kgrp = (ci >> 3) & 1, e = ci & 7;
    int lane = kgrp * 32 + row;
    int dst = (((tap * 8 + ks) * 4 + m) * 64 + lane) * 8 + e;
    wA[dst] = (short)f2bf(w[s]);
}

// ---------------------------------------------------------------------------
// Temporal weight repack (identity ci order, 16x16x32 frag-major, unchanged)
// ---------------------------------------------------------------------------
__global__ void repack_wt2(const float* __restrict__ w, short* __restrict__ wAt) {
    int s = blockIdx.x * 256 + threadIdx.x;
    if (s >= 128 * 128 * 3) return;
    int o = s / 384, r = s % 384, i = r / 3, tap = r % 3;
    int dst = tap * 16384 + (o >> 4) * 2048 + (i >> 5) * 512 +
              ((i >> 3) & 3) * 128 + (o & 15) * 8 + (i & 7);
    wAt[dst] = (short)f2bf(w[s]);
}

// ---------------------------------------------------------------------------
// Spatial 3x3 conv via mfma_f32_32x32x16_bf16. grid (4, 512), block 512.
// Block: 8 rows x 128 co = 224 px = 7 exact 32-px tiles.
// LDS: x window [10][30 st][128 ci] bf16 (76.8 KB, slot swizzle
// slot'=slot^(st&15)) + A double buffer 2x32 KB (tap-granular, staged via
// global_load_lds by ALL waves -> weights cross L2 ONCE per block instead of
// 8x per-wave streams). Waves: ch(2 co-halves) x pg(4): 64 co (m=2) x 2 tiles.
// Per tap: issue A-stage(tap+1) -> compute (A ds_read linear + B ds_read
// swizzled, 32 MFMAs) -> barrier (drains gld_lds, publishes next A buf).
// Epilogue: acc -> LDS bounce -> 128B-contiguous u16x8 stores.
// ---------------------------------------------------------------------------
__global__ __launch_bounds__(512) void spatial_mfma(
    const float* __restrict__ x, const short* __restrict__ wA,
    const float* __restrict__ b_sp, unsigned short* __restrict__ yT)
{
    __shared__ __align__(16) char lds_all[76800 + 2 * 32768];   // 142336 B
    char* xsb = lds_all;
    char* abufs = lds_all + 76800;
    const int t = blockIdx.y;
    const int r0 = blockIdx.x * 8;
    const int rows = (28 - r0 < 8) ? (28 - r0) : 8;
    const int pxcnt = rows * 28;
    const int tid = threadIdx.x;

    // ---- stage 10-row x window, conflict-free writes (lane = ci-pair) ----
    for (int u = tid; u < 4480; u += 512) {
        int cp = u & 63, q = u >> 6;         // q 0..69
        int rl = q / 7, g = q % 7;
        int rr = r0 - 1 + rl;
        float4 f0 = make_float4(0.f, 0.f, 0.f, 0.f), f1 = f0;
        if (rr >= 0 && rr < 28) {
            const float* px0 = &x[((size_t)(t * CH + 2 * cp)) * HWP + rr * 28 + g * 4];
            f0 = *(const float4*)px0;
            f1 = *(const float4*)(px0 + HWP);
        }
        unsigned u0[4] = {__builtin_bit_cast(unsigned, f0.x), __builtin_bit_cast(unsigned, f0.y),
                          __builtin_bit_cast(unsigned, f0.z), __builtin_bit_cast(unsigned, f0.w)};
        unsigned u1[4] = {__builtin_bit_cast(unsigned, f1.x), __builtin_bit_cast(unsigned, f1.y),
                          __builtin_bit_cast(unsigned, f1.z), __builtin_bit_cast(unsigned, f1.w)};
        int stb = rl * 30 + g * 4 + 1;
#pragma unroll
        for (int j = 0; j < 4; ++j) {
            int st = stb + j;
            unsigned val = __builtin_amdgcn_perm(u1[j], u0[j], 0x07060302u);
            int addr = (st << 8) | (((cp >> 2) ^ (st & 15)) << 4) | ((cp & 3) << 2);
            *(unsigned*)(xsb + addr) = val;
        }
    }
    // ---- zero pad columns: st = r*30 + {0,29}, r = 0..9 ----
    for (int v = tid; v < 1280; v += 512) {
        int cp = v & 63, k = v >> 6;         // k 0..19
        int st = (k >> 1) * 30 + (k & 1) * 29;
        int addr = (st << 8) | (((cp >> 2) ^ (st & 15)) << 4) | ((cp & 3) << 2);
        *(unsigned*)(xsb + addr) = 0u;
    }

    // ---- A-stage: 2048 x 16B per tap, wave-uniform LDS dest + lane x 16 ----
    const int wuni = (tid & ~63) * 16;        // wid*64*16, wave-uniform
    auto stageA = [&](int tap, int s) {
        char* ab = abufs + s * 32768;
#pragma unroll
        for (int k = 0; k < 4; ++k) {
            const char* g = (const char*)wA + tap * 32768 + (k * 512 + tid) * 16;
            gld_lds16(g, ab + k * 8192 + wuni);
        }
    };
    stageA(0, 0);
    __syncthreads();                          // publishes x window + A buf 0

    const int wid = tid >> 6, l = tid & 63;
    const int l31 = l & 31, bb5 = l >> 5;
    const int ch = wid & 1, pg = wid >> 1;
    const int ch2 = ch * 2;
    const int tI0 = pg * 2, tI1 = pg * 2 + 1;

    const int p0 = tI0 * 32 + l31;
    const int p1 = tI1 * 32 + l31;
    const bool ok1t = (tI1 < 7);
    const int pc0 = (p0 < pxcnt) ? p0 : 0;
    const int pc1 = (ok1t && p1 < pxcnt) ? p1 : 0;
    const int st0_0 = (pc0 / 28 + 1) * 30 + pc0 % 28 + 1;
    const int st0_1 = (pc1 / 28 + 1) * 30 + pc1 % 28 + 1;

    f32x16 zz = {};
    f32x16 acc00 = zz, acc10 = zz;           // [m][tile0]
    f32x16 acc01 = zz, acc11 = zz;           // [m][tile1]

    const int l16 = l << 4;

#pragma unroll
    for (int tap = 0; tap < 9; ++tap) {
        // issue next tap's A-stage first (T3: stage before compute)
        if (tap < 8) stageA(tap + 1, (tap + 1) & 1);

        const int off = (tap / 3 - 1) * 30 + (tap % 3) - 1;
        const int stv0 = st0_0 + off, stv1 = st0_1 + off;
        const int rb0 = stv0 << 8, sw0 = stv0 & 15;
        const int rb1 = stv1 << 8, sw1 = stv1 & 15;
        const char* ab = abufs + (tap & 1) * 32768;

#pragma unroll
        for (int ks = 0; ks < 8; ++ks) {
            i32x4 a0 = *(const i32x4*)(ab + (ks * 4 + ch2) * 1024 + l16);
            i32x4 a1 = *(const i32x4*)(ab + (ks * 4 + ch2 + 1) * 1024 + l16);
            i32x4 b0 = ldB(xsb, rb0, sw0, ks * 2 + bb5);
            i32x4 b1 = ldB(xsb, rb1, sw1, ks * 2 + bb5);
            __builtin_amdgcn_s_setprio(1);
            acc00 = MFMA32(BC8(a0), BC8(b0), acc00);
            acc10 = MFMA32(BC8(a1), BC8(b0), acc10);
            acc01 = MFMA32(BC8(a0), BC8(b1), acc01);
            acc11 = MFMA32(BC8(a1), BC8(b1), acc11);
            __builtin_amdgcn_s_setprio(0);
        }
        // barrier: drains this wave's gld_lds (compiler emits vmcnt(0)) and
        // publishes A buf (tap+1)&1; also guards buf reuse next iteration.
        __syncthreads();
    }

    // ---- epilogue: window dead; bounce acc through LDS for contiguity ----
    const int wbase = wid * 8704;             // 2 tiles x 32 px x 136 B
#pragma unroll
    for (int mi = 0; mi < 2; ++mi) {
#pragma unroll
        for (int r2 = 0; r2 < 4; ++r2) {
            int cb = (ch2 + mi) * 32 + 8 * r2 + 4 * bb5;
            float4 bs = *(const float4*)&b_sp[cb];
            float bsa[4] = {bs.x, bs.y, bs.z, bs.w};
            u16x4 k0, k1;
#pragma unroll
            for (int q = 0; q < 4; ++q) {
                k0[q] = f2bf((mi ? acc10[r2 * 4 + q] : acc00[r2 * 4 + q]) + bsa[q]);
                k1[q] = f2bf((mi ? acc11[r2 * 4 + q] : acc01[r2 * 4 + q]) + bsa[q]);
            }
            int co_off = (mi * 32 + 8 * r2 + 4 * bb5) * 2;   // within 64-ch half
            *(u16x4*)(xsb + wbase + l31 * 136 + co_off) = k0;
            *(u16x4*)(xsb + wbase + 4352 + l31 * 136 + co_off) = k1;
        }
    }
    // wave-private region: compiler inserts lgkmcnt before dependent reads
#pragma unroll
    for (int tt2 = 0; tt2 < 2; ++tt2) {
        int tI = tt2 ? tI1 : tI0;
#pragma unroll
        for (int j = 0; j < 4; ++j) {
            int idx = j * 64 + l;
            int pxl = idx >> 3, sub = idx & 7;
            u16x8 v = *(const u16x8*)(xsb + wbase + tt2 * 4352 + pxl * 136 + sub * 16);
            int p = tI * 32 + pxl;
            if (tI < 7 && p < pxcnt) {
                char* dst = (char*)yT + ((size_t)t * HWP + r0 * 28 + p) * 256 +
                            ch * 128 + sub * 16;
                *(u16x8*)dst = v;
            }
        }
    }
}

// ---------------------------------------------------------------------------
// Ragged temporal conv: 4-wave blocks, async LDS-staged B, double-buffered.
// grid (7, 512), block 256. (unchanged — near HBM roofline)
// ---------------------------------------------------------------------------
__global__ __launch_bounds__(256, 4) void temporal_mfma(
    const unsigned short* __restrict__ yT, const short* __restrict__ wAt,
    const float* __restrict__ b_t, const float* __restrict__ alpha,
    const float* __restrict__ x, const int* __restrict__ vid_lens,
    float* __restrict__ out)
{
    __shared__ __align__(16) char ldsT[29696];   // 2x14336 stage | 4x7424 epi

    const int chunk = blockIdx.x, t = blockIdx.y;
    const int tid = threadIdx.x, wid = tid >> 6, l = tid & 63;
    const int l15 = l & 15, kgrp = l >> 4;
    const int sx = l15 & 7;

    bool isS = false, isE = false;
    {
        int cum = 0;
        for (int s = 0; s < NSEG; ++s) {
            if (t == cum) isS = true;
            cum += vid_lens[s];
            if (t == cum - 1) isE = true;
        }
    }
    const bool tapAct[3] = {!isS, true, !isE};

    auto stage = [&](int s) {
        int tap = s >> 1, kp = s & 1;
        if (!tapAct[tap]) return;
        int tp = t + tap - 1;
        const char* yb = (const char*)yT + (size_t)tp * HWP * 256;
        char* buf = ldsT + (s & 1) * 14336;
#pragma unroll
        for (int r = 0; r < 4; ++r) {
            int c = r * 256 + wid * 64 + l;
            if (r < 3 || wid < 2) {                    // c < 896, wave-uniform
                int px = c >> 3, sp = c & 7;
                int ssrc = sp ^ (px & 7);
                const char* g = yb + ((size_t)(chunk * 112 + px)) * 256 + kp * 128 + ssrc * 16;
                char* ldst = buf + (r * 256 + wid * 64) * 16;
                gld_lds16(g, ldst);
            }
        }
    };

    f32x4 acc[2][7];
#pragma unroll
    for (int m = 0; m < 2; ++m)
#pragma unroll
        for (int n = 0; n < 7; ++n) acc[m][n] = (f32x4){0.f, 0.f, 0.f, 0.f};

    const bf16x8* wAv = (const bf16x8*)wAt;

    stage(0);
    __syncthreads();

    for (int s = 0; s < 6; ++s) {
        if (s < 5) stage(s + 1);
        int tap = s >> 1, kp = s & 1;
        if (tapAct[tap]) {
            const char* buf = ldsT + (s & 1) * 14336;
            bf16x8 a[2][2];
#pragma unroll
            for (int m = 0; m < 2; ++m)
#pragma unroll
                for (int k1 = 0; k1 < 2; ++k1)
                    a[m][k1] = wAv[((tap * 8 + wid * 2 + m) * 4 + kp * 2 + k1) * 64 + l];
            __builtin_amdgcn_s_setprio(1);
#pragma unroll
            for (int k1 = 0; k1 < 2; ++k1) {
#pragma unroll
                for (int nf = 0; nf < 7; ++nf) {
                    int addr = (nf * 16 + l15) * 128 + ((k1 * 4 + kgrp) ^ sx) * 16;
                    i32x4 bi = *(const i32x4*)(buf + addr);
                    bf16x8 b = __builtin_bit_cast(bf16x8, bi);
                    acc[0][nf] = __builtin_amdgcn_mfma_f32_16x16x32_bf16(a[0][k1], b, acc[0][nf], 0, 0, 0);
                    acc[1][nf] = __builtin_amdgcn_mfma_f32_16x16x32_bf16(a[1][k1], b, acc[1][nf], 0, 0, 0);
                }
            }
            __builtin_amdgcn_s_setprio(0);
        }
        __syncthreads();
    }

    // ---- epilogue: LDS transpose -> coalesced bias/PReLU/residual/store ----
    float* fl = (float*)ldsT;
    const int wbase = wid * 1856;            // 16 co x 116 px-stride floats
#pragma unroll
    for (int m = 0; m < 2; ++m) {
#pragma unroll
        for (int nf = 0; nf < 7; ++nf)
#pragma unroll
            for (int rr = 0; rr < 4; ++rr)
                fl[wbase + (kgrp * 4 + rr) * 116 + nf * 16 + l15] = acc[m][nf][rr];
#pragma unroll
        for (int j = 0; j < 7; ++j) {
            int idx = j * 64 + l;
            int co_r = idx / 28, q = idx % 28;
            f32x4 v4 = *(const f32x4*)&fl[wbase + co_r * 116 + q * 4];
            int co_g = wid * 32 + m * 16 + co_r;
            float bt = b_t[co_g], al = alpha[co_g];
            size_t gi = ((size_t)(t * CH + co_g)) * HWP + chunk * 112 + q * 4;
            float4 xv = *(const float4*)&x[gi];
            float xr[4] = {xv.x, xv.y, xv.z, xv.w};
            float rrv[4];
#pragma unroll
            for (int e = 0; e < 4; ++e) {
                float v = v4[e] + bt;
                v = (v >= 0.f) ? v : al * v;
                rrv[e] = v + xr[e];
            }
            *(float4*)&out[gi] = make_float4(rrv[0], rrv[1], rrv[2], rrv[3]);
        }
        __syncthreads();   // all waves done with region before m=1 reuse
    }
}

// ---------------------------------------------------------------------------
__global__ void write_lens(const int* __restrict__ vid_lens, float* __restrict__ out) {
    int i = threadIdx.x;
    if (i < NSEG) out[NOUT + i] = (float)vid_lens[i];
}

// ---------------------------------------------------------------------------
extern "C" void kernel_launch(void* const* d_in, const int* in_sizes, int n_in,
                              void* d_out, int out_size, void* d_ws, size_t ws_size,
                              hipStream_t stream) {
    const float* x        = (const float*)d_in[0];
    const int*   vid_lens = (const int*)d_in[1];
    const float* w_sp     = (const float*)d_in[2];
    const float* b_sp     = (const float*)d_in[3];
    const float* w_t      = (const float*)d_in[4];
    const float* b_t      = (const float*)d_in[5];
    const float* alpha    = (const float*)d_in[6];
    float* out = (float*)d_out;

    unsigned short* yT = (unsigned short*)d_ws;                       // 102,760,448 B
    short* wA  = (short*)((char*)d_ws + 102760448);                   //    294,912 B
    short* wAt = (short*)((char*)d_ws + 102760448 + 294912);          //     98,304 B

    repack_wsp<<<576, 256, 0, stream>>>(w_sp, wA);
    repack_wt2<<<192, 256, 0, stream>>>(w_t, wAt);
    spatial_mfma<<<dim3(4, 512), 512, 0, stream>>>(x, wA, b_sp, yT);
    temporal_mfma<<<dim3(7, 512), 256, 0, stream>>>(yT, wAt, b_t, alpha, x, vid_lens, out);
    write_lens<<<1, 64, 0, stream>>>(vid_lens, out);
}